// Round 9
// baseline (24.033 us; speedup 1.0000x reference)
//
#include <hip/hip_runtime.h>

#define ORD 16
#define LCH 64
#define PCH 16384          // chunks; PCH*LCH = 2^20
#define NB  512            // blocks; CPB own chunks each (2 blocks/CU)
#define CPB 32
#define QT  16             // warm-up chunks (0.6561^16*8 ~ 0.009 trunc err)
#define WCH (CPB + QT)     // 48 window chunks per block
#define NG  (WCH / 4)      // 12 4-chunk scan groups
#define XSTR 84            // xs row stride: 4*odd -> b128 conflict-light
#define YSTR 68            // y_s row stride: 4*odd

__global__ __launch_bounds__(256) void k_arx(const float* __restrict__ u,
                                             const float* __restrict__ A_w,
                                             const float* __restrict__ B_w,
                                             float* __restrict__ out) {
    __shared__ float xs[WCH][XSTR];      // 16.1 KB  (FIR output)
    __shared__ float y_s[CPB][YSTR];     //  8.7 KB
    __shared__ float sR[16][ORD][17];    // 17.4 KB  M^r, r=0..15
    __shared__ float sM16[ORD][17], sM32[ORD][17];
    __shared__ float sG1[ORD][17], sG2[ORD][17], sG3[ORD][17], sG4[ORD][17];
    __shared__ float sW[4][ORD];         // w_q = a . M^(16q)
    __shared__ float sV[ORD][LCH];       // V[j][k] = (a.M^k)[j]
    __shared__ float sd[WCH][17];        // window-chunk end states
    __shared__ float sF[NG][17];         // 4-group inhomogeneous terms
    __shared__ float sS[CPB][17];        // own-chunk entry states
    // total ~59 KB -> 2 blocks/CU

    const int tid = threadIdx.x;
    const int cb  = blockIdx.x * CPB;
    const long gstart = ((long)cb - QT) * LCH;

    // ---- FIR straight from global: xs[w][t] = sum_s b[15-s]*u[.+t+s] ----
    if (tid < WCH * 4) {
        float bb[ORD];
        #pragma unroll
        for (int i = 0; i < ORD; ++i) bb[i] = B_w[i];
        const int w = tid >> 2, t0 = (tid & 3) * 16;
        const long gbase = gstart + (long)w * LCH + t0;
        if (gstart + (long)w * LCH >= 0) {            // block 0 warm-up guard
            float uu[32];
            const float* up = u + gbase;
            #pragma unroll
            for (int m = 0; m < 8; ++m)
                *(float4*)&uu[4 * m] = *(const float4*)(up + 4 * m);
            float xv[16];
            #pragma unroll
            for (int kk = 0; kk < 16; ++kk) {
                float x = 0.f;
                #pragma unroll
                for (int s = 0; s < ORD; ++s) x += bb[15 - s] * uu[kk + s];
                xv[kk] = x;
            }
            #pragma unroll
            for (int m = 0; m < 4; ++m)
                *(float4*)&xs[w][t0 + 4 * m] = *(const float4*)&xv[4 * m];
        }
    }

    // ---- tables ----
    const int ti = tid >> 4, tj = tid & 15;
    sR[0][ti][tj] = (ti == tj) ? 1.f : 0.f;
    sR[1][ti][tj] = (ti == 0) ? A_w[tj] : ((tj == ti - 1) ? 1.f : 0.f);
    if (tid < ORD) sW[0][tid] = A_w[tid];
    __syncthreads();
    int have = 1;
    while (have < 15) {                  // M^2..M^15 by doubling
        const int nn = (have < 15 - have) ? have : (15 - have);
        for (int idx = tid; idx < nn * 256; idx += 256) {
            const int m = (idx >> 8) + 1, ii = (idx >> 4) & 15, jj = idx & 15;
            float acc = 0.f;
            #pragma unroll
            for (int l = 0; l < ORD; ++l) acc += sR[have][ii][l] * sR[m][l][jj];
            sR[have + m][ii][jj] = acc;
        }
        __syncthreads();
        have += nn;
    }
    {   float acc = 0.f;                 // M^16
        #pragma unroll
        for (int l = 0; l < ORD; ++l) acc += sR[15][ti][l] * sR[1][l][tj];
        sM16[ti][tj] = acc; }
    __syncthreads();
    {   float acc = 0.f;                 // M^32 ; sW1
        #pragma unroll
        for (int l = 0; l < ORD; ++l) acc += sM16[ti][l] * sM16[l][tj];
        sM32[ti][tj] = acc;
        if (tid < ORD) {
            float w = 0.f;
            #pragma unroll
            for (int l = 0; l < ORD; ++l) w += sW[0][l] * sM16[l][tid];
            sW[1][tid] = w;
        } }
    __syncthreads();
    {   float acc = 0.f;                 // G = M^64 ; sW2
        #pragma unroll
        for (int l = 0; l < ORD; ++l) acc += sM32[ti][l] * sM32[l][tj];
        sG1[ti][tj] = acc;
        if (tid < ORD) {
            float w = 0.f;
            #pragma unroll
            for (int l = 0; l < ORD; ++l) w += sW[1][l] * sM16[l][tid];
            sW[2][tid] = w;
        } }
    __syncthreads();
    {   float acc = 0.f;                 // G^2 ; sW3
        #pragma unroll
        for (int l = 0; l < ORD; ++l) acc += sG1[ti][l] * sG1[l][tj];
        sG2[ti][tj] = acc;
        if (tid < ORD) {
            float w = 0.f;
            #pragma unroll
            for (int l = 0; l < ORD; ++l) w += sW[2][l] * sM16[l][tid];
            sW[3][tid] = w;
        } }
    __syncthreads();
    {   float a3 = 0.f, a4 = 0.f;        // G^3, G^4
        #pragma unroll
        for (int l = 0; l < ORD; ++l) {
            a3 += sG2[ti][l] * sG1[l][tj];
            a4 += sG2[ti][l] * sG2[l][tj];
        }
        sG3[ti][tj] = a3;
        sG4[ti][tj] = a4; }
    for (int idx = tid; idx < ORD * LCH; idx += 256) {   // V[j][k] = w_q . M^r
        const int k = idx >> 4, jj = idx & 15, q = k >> 4, r = k & 15;
        float acc = 0.f;
        #pragma unroll
        for (int l = 0; l < ORD; ++l) acc += sW[q][l] * sR[r][l][jj];
        sV[jj][k] = acc;
    }
    __syncthreads();

    // ---- serial sim (IIR only): lanes 0..47 own window chunk tid ----
    {
        const int gchunk = cb - QT + tid;
        float yr[ORD];
        #pragma unroll
        for (int i = 0; i < ORD; ++i) yr[i] = 0.f;
        if (tid < WCH && gchunk >= 0) {
            float a[ORD], xv[ORD];
            #pragma unroll
            for (int i = 0; i < ORD; ++i) a[i] = A_w[i];
            for (int k0 = 0; k0 < LCH; k0 += ORD) {
                #pragma unroll
                for (int m = 0; m < 4; ++m)
                    *(float4*)&xv[4 * m] = *(const float4*)&xs[tid][k0 + 4 * m];
                #pragma unroll
                for (int kk = 0; kk < ORD; ++kk) {
                    // 4 parallel chains, a[0]*y[t-1] added LAST (1-FMA x-step)
                    float c0 = xv[kk], c1, c2, c3;
                    c0 += a[1]  * yr[(kk - 2)  & 15];
                    c1  = a[2]  * yr[(kk - 3)  & 15];
                    c2  = a[3]  * yr[(kk - 4)  & 15];
                    c3  = a[4]  * yr[(kk - 5)  & 15];
                    c0 += a[5]  * yr[(kk - 6)  & 15];
                    c1 += a[6]  * yr[(kk - 7)  & 15];
                    c2 += a[7]  * yr[(kk - 8)  & 15];
                    c3 += a[8]  * yr[(kk - 9)  & 15];
                    c0 += a[9]  * yr[(kk - 10) & 15];
                    c1 += a[10] * yr[(kk - 11) & 15];
                    c2 += a[11] * yr[(kk - 12) & 15];
                    c3 += a[12] * yr[(kk - 13) & 15];
                    c0 += a[13] * yr[(kk - 14) & 15];
                    c1 += a[14] * yr[(kk - 15) & 15];
                    c2 += a[15] * yr[(kk - 16) & 15];
                    float y = (c0 + c1) + (c2 + c3);
                    y += a[0] * yr[(kk - 1) & 15];
                    yr[kk] = y;
                }
                if (tid >= QT) {
                    #pragma unroll
                    for (int m = 0; m < 4; ++m)
                        *(float4*)&y_s[tid - QT][k0 + 4 * m] = *(const float4*)&yr[4 * m];
                }
            }
        }
        if (tid < WCH) {
            #pragma unroll
            for (int i = 0; i < ORD; ++i) sd[tid][i] = yr[15 - i];
        }
    }
    __syncthreads();

    // ---- f-groups: f_g = G3.d[4g] + G2.d[4g+1] + G1.d[4g+2] + d[4g+3] ----
    if (tid < NG * ORD) {
        const int g = tid >> 4, jj = tid & 15;
        float acc = sd[4 * g + 3][jj];
        #pragma unroll
        for (int i = 0; i < ORD; ++i) {
            acc += sG3[jj][i] * sd[4 * g][i];
            acc += sG2[jj][i] * sd[4 * g + 1][i];
            acc += sG1[jj][i] * sd[4 * g + 2][i];
        }
        sF[g][jj] = acc;
    }
    __syncthreads();

    // ---- blocked scan: S_{g+1} = G4.S_g + f_g ; 6 iters per wave ----
    {
        const int l = tid & 63, w = tid >> 6;
        const int j = l & 15, q = l >> 4;
        const float g0 = sG4[j][4 * q + 0], g1 = sG4[j][4 * q + 1];
        const float g2 = sG4[j][4 * q + 2], g3 = sG4[j][4 * q + 3];
        float S = 0.f;                   // entry state of window group 2w
        #pragma unroll
        for (int i = 0; i < 6; ++i) {
            if (i >= 4 && l < 16) sS[8 * w + 4 * (i - 4)][j] = S;
            float p = (g0 * __shfl(S, 4 * q + 0, 16) + g1 * __shfl(S, 4 * q + 1, 16))
                    + (g2 * __shfl(S, 4 * q + 2, 16) + g3 * __shfl(S, 4 * q + 3, 16));
            p += __shfl_xor(p, 16);
            p += __shfl_xor(p, 32);
            S = p + sF[2 * w + i][j];
        }
    }
    // ---- reconstruct S at c%4 != 0 (data-parallel, 3 rounds) ----
    #pragma unroll
    for (int r = 1; r <= 3; ++r) {
        __syncthreads();
        if (tid < (CPB / 4) * ORD) {
            const int g = tid >> 4, jj = tid & 15;
            float acc = sd[QT + 4 * g + r - 1][jj];
            #pragma unroll
            for (int i = 0; i < ORD; ++i) acc += sG1[jj][i] * sS[4 * g + r - 1][i];
            sS[4 * g + r][jj] = acc;
        }
    }
    __syncthreads();

    // ---- correction + store: out = y_loc + V_k . S_c (b128 / dwordx4) ----
    float4* out4 = (float4*)(out + (long)cb * LCH);
    #pragma unroll
    for (int it = 0; it < (CPB * LCH) / (4 * 256); ++it) {
        const int f = it * 256 + tid;
        const int row = f >> 4, k4 = f & 15;
        float4 y = *(const float4*)&y_s[row][4 * k4];
        #pragma unroll
        for (int jj = 0; jj < ORD; ++jj) {
            const float s = sS[row][jj];
            const float4 vv = *(const float4*)&sV[jj][4 * k4];
            y.x += vv.x * s; y.y += vv.y * s; y.z += vv.z * s; y.w += vv.w * s;
        }
        out4[f] = y;
    }
}

extern "C" void kernel_launch(void* const* d_in, const int* in_sizes, int n_in,
                              void* d_out, int out_size, void* d_ws, size_t ws_size,
                              hipStream_t stream) {
    const float* u = (const float*)d_in[0];
    const float* A = (const float*)d_in[1];
    const float* B = (const float*)d_in[2];
    float* out = (float*)d_out;
    k_arx<<<NB, 256, 0, stream>>>(u, A, B, out);
}

// Round 10
// 17.250 us; speedup vs baseline: 1.3932x; 1.3932x over previous
//
#include <hip/hip_runtime.h>

#define ORD 16
#define LCH 64
#define PCH 16384          // chunks; PCH*LCH = 2^20
#define NB  256            // blocks; CPB own chunks each
#define CPB 64
#define QT  16             // warm-up chunks (0.6561^16*8 ~ 0.009 trunc err)
#define WCH (CPB + QT)     // 80 window chunks per block
#define NG  (WCH / 4)      // 20 4-chunk scan groups
#define XSTR 84            // xs row stride
#define YSTR 68            // y_s row stride

// Tables via companion-matrix identity: row i of M^n = v_{n-1-i}, v_k = a.M^k.
// So V, G1..G4 all come from v_0..v_255 (sVt), built by v-doubling on waves
// 2-3 CONCURRENTLY with the IIR on waves 0-1 (LDS spin-flag sync, no block
// barrier inside the divergent region).

__global__ __launch_bounds__(256) void k_arx(const float* __restrict__ u,
                                             const float* __restrict__ A_w,
                                             const float* __restrict__ B_w,
                                             float* __restrict__ out) {
    __shared__ float xs[WCH][XSTR];      // 26.9 KB  FIR output
    __shared__ float y_s[CPB][YSTR];     // 17.4 KB  local y
    __shared__ float sVt[256][17];       // 17.4 KB  v_k rows
    __shared__ float sV[ORD][LCH];       //  4.0 KB  V transposed (correction)
    __shared__ float sd[WCH][17];        //  5.4 KB  chunk end states
    __shared__ float sF[NG][17];         //  1.4 KB  4-group terms
    __shared__ float sS[CPB][17];        //  4.4 KB  entry states
    __shared__ int tflag;

    const int tid = threadIdx.x;
    const int cb  = blockIdx.x * CPB;
    const long gstart = ((long)cb - QT) * LCH;

    // ---- FIR from global: xs[w][t] = sum_s b[15-s]*u[.]; 320 items ----
    {
        float bb[ORD];
        #pragma unroll
        for (int i = 0; i < ORD; ++i) bb[i] = B_w[i];
        #pragma unroll
        for (int pass = 0; pass < 2; ++pass) {
            const int idx = (pass == 0) ? tid : tid + 64;  // pass2: wave 3 -> 256..319
            if (pass == 1 && tid < 192) continue;
            const int w = idx >> 2, t0 = (idx & 3) * 16;
            const long grow = gstart + (long)w * LCH;
            if (grow >= 0) {
                float uu[32];
                const float* up = u + grow + t0;
                #pragma unroll
                for (int m = 0; m < 8; ++m)
                    *(float4*)&uu[4 * m] = *(const float4*)(up + 4 * m);
                float xv[16];
                #pragma unroll
                for (int kk = 0; kk < 16; ++kk) {
                    float x = 0.f;
                    #pragma unroll
                    for (int s = 0; s < ORD; ++s) x += bb[15 - s] * uu[kk + s];
                    xv[kk] = x;
                }
                #pragma unroll
                for (int m = 0; m < 4; ++m)
                    *(float4*)&xs[w][t0 + 4 * m] = *(const float4*)&xv[4 * m];
            }
        }
    }
    if (tid == 0) tflag = 0;
    __syncthreads();

    if (tid < 128) {
        // ---- IIR (waves 0-1): lanes 0..79 own window chunk tid ----
        const int gchunk = cb - QT + tid;
        float yr[ORD];
        #pragma unroll
        for (int i = 0; i < ORD; ++i) yr[i] = 0.f;
        if (tid < WCH && gchunk >= 0) {
            float a[ORD], xv[ORD];
            #pragma unroll
            for (int i = 0; i < ORD; ++i) a[i] = A_w[i];
            for (int k0 = 0; k0 < LCH; k0 += ORD) {
                #pragma unroll
                for (int m = 0; m < 4; ++m)
                    *(float4*)&xv[4 * m] = *(const float4*)&xs[tid][k0 + 4 * m];
                #pragma unroll
                for (int kk = 0; kk < ORD; ++kk) {
                    // 4 parallel chains; a[0]*y[t-1] added LAST (1-FMA x-step)
                    float c0 = xv[kk], c1, c2, c3;
                    c0 += a[1]  * yr[(kk - 2)  & 15];
                    c1  = a[2]  * yr[(kk - 3)  & 15];
                    c2  = a[3]  * yr[(kk - 4)  & 15];
                    c3  = a[4]  * yr[(kk - 5)  & 15];
                    c0 += a[5]  * yr[(kk - 6)  & 15];
                    c1 += a[6]  * yr[(kk - 7)  & 15];
                    c2 += a[7]  * yr[(kk - 8)  & 15];
                    c3 += a[8]  * yr[(kk - 9)  & 15];
                    c0 += a[9]  * yr[(kk - 10) & 15];
                    c1 += a[10] * yr[(kk - 11) & 15];
                    c2 += a[11] * yr[(kk - 12) & 15];
                    c3 += a[12] * yr[(kk - 13) & 15];
                    c0 += a[13] * yr[(kk - 14) & 15];
                    c1 += a[14] * yr[(kk - 15) & 15];
                    c2 += a[15] * yr[(kk - 16) & 15];
                    float y = (c0 + c1) + (c2 + c3);
                    y += a[0] * yr[(kk - 1) & 15];
                    yr[kk] = y;
                }
                if (tid >= QT) {
                    #pragma unroll
                    for (int m = 0; m < 4; ++m)
                        *(float4*)&y_s[tid - QT][k0 + 4 * m] = *(const float4*)&yr[4 * m];
                }
            }
        }
        if (tid < WCH) {
            #pragma unroll
            for (int i = 0; i < ORD; ++i) sd[tid][i] = yr[15 - i];
        }
    } else {
        // ---- tables (waves 2-3): v-doubling, v_{s+r} = v_r . M^s ----
        const int ll = tid - 128;            // 0..127
        int syncnum = 0;
        volatile int* vf = &tflag;
        // seed v_0 = a (wave 2)
        if (ll < 16) sVt[0][ll] = A_w[ll];
        // small rounds s=1,2,4,8 (<=128 elems); cross-wave dep first at s=8
        for (int s = 1; s <= 8; s <<= 1) {
            if (s == 8) {
                ++syncnum;
                if ((tid & 63) == 0) atomicAdd(&tflag, 1);
                while (*vf < 2 * syncnum) __builtin_amdgcn_s_sleep(1);
                asm volatile("" ::: "memory");
            }
            if (ll < s * 16) {
                const int r = ll >> 4, j = ll & 15;
                float acc = (j + s < 16) ? sVt[r][j + s] : 0.f;
                for (int i = 0; i < s; ++i) acc += sVt[r][i] * sVt[s - 1 - i][j];
                sVt[s + r][j] = acc;
            }
        }
        // big rounds s=16,32,64,128: col-preload, both waves split r-space
        for (int s = 16; s <= 128; s <<= 1) {
            ++syncnum;
            if ((tid & 63) == 0) atomicAdd(&tflag, 1);
            while (*vf < 2 * syncnum) __builtin_amdgcn_s_sleep(1);
            asm volatile("" ::: "memory");
            const int j = ll & 15, rb = ll >> 4;     // rb 0..7
            float cols[16];
            #pragma unroll
            for (int i = 0; i < 16; ++i) cols[i] = sVt[s - 1 - i][j];
            for (int r = rb; r < s; r += 8) {
                float acc = 0.f;
                #pragma unroll
                for (int i = 0; i < 16; ++i) acc += sVt[r][i] * cols[i];
                sVt[s + r][j] = acc;
            }
        }
    }
    __syncthreads();

    // ---- f-groups: f_g = G3.d[4g] + G2.d[4g+1] + G1.d[4g+2] + d[4g+3] ----
    // G_m rows from sVt: G3[j][i]=v_{191-j}[i], G2=v_{127-j}, G1=v_{63-j}
    for (int idx = tid; idx < NG * ORD; idx += 256) {
        const int g = idx >> 4, jj = idx & 15;
        float acc = sd[4 * g + 3][jj];
        #pragma unroll
        for (int i = 0; i < ORD; ++i) {
            acc += sVt[191 - jj][i] * sd[4 * g][i];
            acc += sVt[127 - jj][i] * sd[4 * g + 1][i];
            acc += sVt[63  - jj][i] * sd[4 * g + 2][i];
        }
        sF[g][jj] = acc;
    }
    // V transpose for correction: sV[jj][k] = v_k[jj]
    for (int e = tid; e < ORD * LCH; e += 256) {
        const int jj = e >> 6, k = e & 63;
        sV[jj][k] = sVt[k][jj];
    }
    __syncthreads();

    // ---- blocked scan: S_{g+1} = G4.S_g + f_g ; G4[j][l] = v_{255-j}[l] ----
    {
        const int l = tid & 63, w = tid >> 6;
        const int j = l & 15, q = l >> 4;
        const float g0 = sVt[255 - j][4 * q + 0], g1 = sVt[255 - j][4 * q + 1];
        const float g2 = sVt[255 - j][4 * q + 2], g3 = sVt[255 - j][4 * q + 3];
        float S = 0.f;                   // entry state of window group 4w
        #pragma unroll
        for (int i = 0; i < 8; ++i) {
            if (i >= 4 && l < 16) sS[16 * w + 4 * (i - 4)][j] = S;
            float p = (g0 * __shfl(S, 4 * q + 0, 16) + g1 * __shfl(S, 4 * q + 1, 16))
                    + (g2 * __shfl(S, 4 * q + 2, 16) + g3 * __shfl(S, 4 * q + 3, 16));
            p += __shfl_xor(p, 16);
            p += __shfl_xor(p, 32);
            S = p + sF[4 * w + i][j];
        }
    }
    // ---- reconstruct S at c%4 != 0: S = G1.S_prev + d_prev ----
    #pragma unroll
    for (int r = 1; r <= 3; ++r) {
        __syncthreads();
        const int g = tid >> 4, jj = tid & 15;
        float acc = sd[QT + 4 * g + r - 1][jj];
        #pragma unroll
        for (int i = 0; i < ORD; ++i) acc += sVt[63 - jj][i] * sS[4 * g + r - 1][i];
        sS[4 * g + r][jj] = acc;
    }
    __syncthreads();

    // ---- correction + store: out = y_loc + V_k . S_c (b128 / dwordx4) ----
    float4* out4 = (float4*)(out + (long)cb * LCH);
    #pragma unroll
    for (int it = 0; it < 4; ++it) {
        const int f = it * 256 + tid;
        const int row = f >> 4, k4 = f & 15;
        float4 y = *(const float4*)&y_s[row][4 * k4];
        #pragma unroll
        for (int jj = 0; jj < ORD; ++jj) {
            const float s = sS[row][jj];
            const float4 vv = *(const float4*)&sV[jj][4 * k4];
            y.x += vv.x * s; y.y += vv.y * s; y.z += vv.z * s; y.w += vv.w * s;
        }
        out4[f] = y;
    }
}

extern "C" void kernel_launch(void* const* d_in, const int* in_sizes, int n_in,
                              void* d_out, int out_size, void* d_ws, size_t ws_size,
                              hipStream_t stream) {
    const float* u = (const float*)d_in[0];
    const float* A = (const float*)d_in[1];
    const float* B = (const float*)d_in[2];
    float* out = (float*)d_out;
    k_arx<<<NB, 256, 0, stream>>>(u, A, B, out);
}

// Round 11
// 15.318 us; speedup vs baseline: 1.5689x; 1.1262x over previous
//
#include <hip/hip_runtime.h>

#define ORD 16
#define LCH 64
#define PCH 16384          // chunks; PCH*LCH = 2^20
#define NB  256            // blocks; CPB own chunks each
#define CPB 64
#define QT  16             // warm-up chunks (0.6561^16*8 ~ 0.009 trunc err)
#define WCH (CPB + QT)     // 80 window chunks per block
#define NG  (WCH / 4)      // 20 4-chunk scan groups
#define XSTR 84            // xs row stride (336B, 16B-aligned)
#define YSTR 68            // y_s row stride (272B, 16B-aligned)
#define TSTR 20            // table row stride (80B, 16B-aligned, bank-spread)

// Tables via companion identity: row i of M^n = v_{n-1-i}, v_k = a.M^k.
// V, G1..G4 all come from v_0..v_255 (sVt), built by v-doubling on waves 2-3
// CONCURRENTLY with the IIR on waves 0-1 (LDS spin-flag sync).
// All hot table rows are read as ds_read_b128 into registers (stride 20).

__global__ __launch_bounds__(256) void k_arx(const float* __restrict__ u,
                                             const float* __restrict__ A_w,
                                             const float* __restrict__ B_w,
                                             float* __restrict__ out) {
    __shared__ float xs[WCH][XSTR];      // 26.9 KB  FIR output
    __shared__ float y_s[CPB][YSTR];     // 17.4 KB  local y
    __shared__ float sVt[256][TSTR];     // 20.5 KB  v_k rows
    __shared__ float sdrev[WCH][TSTR];   //  6.4 KB  end states, sdrev[c][p]=y_loc[48+p]
    __shared__ float sF[NG][17];         //  1.4 KB  4-group terms
    __shared__ float sS[CPB][TSTR];      //  5.1 KB  entry states
    __shared__ int tflag;

    const int tid = threadIdx.x;
    const int cb  = blockIdx.x * CPB;
    const long gstart = ((long)cb - QT) * LCH;

    // ---- FIR from global: xs[w][t] = sum_s b[15-s]*u[.]; 320 items ----
    {
        float bb[ORD];
        #pragma unroll
        for (int i = 0; i < ORD; ++i) bb[i] = B_w[i];
        #pragma unroll
        for (int pass = 0; pass < 2; ++pass) {
            const int idx = (pass == 0) ? tid : tid + 64;  // pass2: wave3 -> 256..319
            if (pass == 1 && tid < 192) continue;
            const int w = idx >> 2, t0 = (idx & 3) * 16;
            const long grow = gstart + (long)w * LCH;
            if (grow >= 0) {
                float uu[32];
                const float* up = u + grow + t0;
                #pragma unroll
                for (int m = 0; m < 8; ++m)
                    *(float4*)&uu[4 * m] = *(const float4*)(up + 4 * m);
                float xv[16];
                #pragma unroll
                for (int kk = 0; kk < 16; ++kk) {
                    float x = 0.f;
                    #pragma unroll
                    for (int s = 0; s < ORD; ++s) x += bb[15 - s] * uu[kk + s];
                    xv[kk] = x;
                }
                #pragma unroll
                for (int m = 0; m < 4; ++m)
                    *(float4*)&xs[w][t0 + 4 * m] = *(const float4*)&xv[4 * m];
            }
        }
    }
    if (tid == 0) tflag = 0;
    __syncthreads();

    if (tid < 128) {
        // ---- IIR (waves 0-1): lanes 0..79 own window chunk tid ----
        const int gchunk = cb - QT + tid;
        float yr[ORD];
        #pragma unroll
        for (int i = 0; i < ORD; ++i) yr[i] = 0.f;
        if (tid < WCH && gchunk >= 0) {
            float a[ORD], xv[ORD];
            #pragma unroll
            for (int i = 0; i < ORD; ++i) a[i] = A_w[i];
            for (int k0 = 0; k0 < LCH; k0 += ORD) {
                #pragma unroll
                for (int m = 0; m < 4; ++m)
                    *(float4*)&xv[4 * m] = *(const float4*)&xs[tid][k0 + 4 * m];
                #pragma unroll
                for (int kk = 0; kk < ORD; ++kk) {
                    // 4 parallel chains; a[0]*y[t-1] added LAST (1-FMA x-step)
                    float c0 = xv[kk], c1, c2, c3;
                    c0 += a[1]  * yr[(kk - 2)  & 15];
                    c1  = a[2]  * yr[(kk - 3)  & 15];
                    c2  = a[3]  * yr[(kk - 4)  & 15];
                    c3  = a[4]  * yr[(kk - 5)  & 15];
                    c0 += a[5]  * yr[(kk - 6)  & 15];
                    c1 += a[6]  * yr[(kk - 7)  & 15];
                    c2 += a[7]  * yr[(kk - 8)  & 15];
                    c3 += a[8]  * yr[(kk - 9)  & 15];
                    c0 += a[9]  * yr[(kk - 10) & 15];
                    c1 += a[10] * yr[(kk - 11) & 15];
                    c2 += a[11] * yr[(kk - 12) & 15];
                    c3 += a[12] * yr[(kk - 13) & 15];
                    c0 += a[13] * yr[(kk - 14) & 15];
                    c1 += a[14] * yr[(kk - 15) & 15];
                    c2 += a[15] * yr[(kk - 16) & 15];
                    float y = (c0 + c1) + (c2 + c3);
                    y += a[0] * yr[(kk - 1) & 15];
                    yr[kk] = y;
                }
                if (tid >= QT) {
                    #pragma unroll
                    for (int m = 0; m < 4; ++m)
                        *(float4*)&y_s[tid - QT][k0 + 4 * m] = *(const float4*)&yr[4 * m];
                }
            }
        }
        if (tid < WCH) {
            // yr[m] = y_loc[48+m]  (steps 48..63 wrote slots 0..15)
            #pragma unroll
            for (int m = 0; m < 4; ++m)
                *(float4*)&sdrev[tid][4 * m] = *(const float4*)&yr[4 * m];
        }
    } else {
        // ---- tables (waves 2-3): v-doubling, v_{s+r} = v_r . M^s ----
        const int ll = tid - 128;            // 0..127
        int syncnum = 0;
        volatile int* vf = &tflag;
        if (ll < 16) sVt[0][ll] = A_w[ll];   // v_0 = a
        // small rounds s=1,2,4,8; cross-wave dep first at s=8
        for (int s = 1; s <= 8; s <<= 1) {
            if (s == 8) {
                ++syncnum;
                if ((tid & 63) == 0) atomicAdd(&tflag, 1);
                while (*vf < 2 * syncnum) __builtin_amdgcn_s_sleep(1);
                asm volatile("" ::: "memory");
            }
            if (ll < s * 16) {
                const int r = ll >> 4, j = ll & 15;
                float acc = (j + s < 16) ? sVt[r][j + s] : 0.f;
                for (int i = 0; i < s; ++i) acc += sVt[r][i] * sVt[s - 1 - i][j];
                sVt[s + r][j] = acc;
            }
        }
        // big rounds s=16,32,64,128: col-preload + b128 row reads
        for (int s = 16; s <= 128; s <<= 1) {
            ++syncnum;
            if ((tid & 63) == 0) atomicAdd(&tflag, 1);
            while (*vf < 2 * syncnum) __builtin_amdgcn_s_sleep(1);
            asm volatile("" ::: "memory");
            const int j = ll & 15, rb = ll >> 4;     // rb 0..7
            float cols[16];
            #pragma unroll
            for (int i = 0; i < 16; ++i) cols[i] = sVt[s - 1 - i][j];
            for (int r = rb; r < s; r += 8) {
                float vr[16];
                #pragma unroll
                for (int m = 0; m < 4; ++m)
                    *(float4*)&vr[4 * m] = *(const float4*)&sVt[r][4 * m];
                float acc = 0.f;
                #pragma unroll
                for (int i = 0; i < 16; ++i) acc += vr[i] * cols[i];
                sVt[s + r][j] = acc;
            }
        }
    }
    __syncthreads();

    // ---- f-groups + reconstruct share per-thread register G-rows ----
    const int jj = tid & 15;
    float g3r[16], g2r[16], g1r[16];
    #pragma unroll
    for (int m = 0; m < 4; ++m) {
        *(float4*)&g3r[4 * m] = *(const float4*)&sVt[191 - jj][4 * m];  // G3 row jj
        *(float4*)&g2r[4 * m] = *(const float4*)&sVt[127 - jj][4 * m];  // G2 row jj
        *(float4*)&g1r[4 * m] = *(const float4*)&sVt[63  - jj][4 * m];  // G1 row jj
    }
    // f_g = G3.d[4g] + G2.d[4g+1] + G1.d[4g+2] + d[4g+3]; d[i]=sdrev[.][15-i]
    for (int idx = tid; idx < NG * ORD; idx += 256) {   // 2nd item: same jj
        const int g = idx >> 4;
        float dd0[16], dd1[16], dd2[16];
        #pragma unroll
        for (int m = 0; m < 4; ++m) {
            *(float4*)&dd0[4 * m] = *(const float4*)&sdrev[4 * g + 0][4 * m];
            *(float4*)&dd1[4 * m] = *(const float4*)&sdrev[4 * g + 1][4 * m];
            *(float4*)&dd2[4 * m] = *(const float4*)&sdrev[4 * g + 2][4 * m];
        }
        float acc = sdrev[4 * g + 3][15 - jj];
        #pragma unroll
        for (int i = 0; i < 16; ++i)
            acc += g3r[i] * dd0[15 - i] + g2r[i] * dd1[15 - i] + g1r[i] * dd2[15 - i];
        sF[g][jj] = acc;
    }
    __syncthreads();

    // ---- blocked scan: S_{g+1} = G4.S_g + f_g ; G4 row j = v_{255-j} ----
    {
        const int l = tid & 63, w = tid >> 6;
        const int j = l & 15, q = l >> 4;
        const float4 gr = *(const float4*)&sVt[255 - j][4 * q];
        float S = 0.f;                   // entry state of window group 4w
        #pragma unroll
        for (int i = 0; i < 8; ++i) {
            if (i >= 4 && l < 16) sS[16 * w + 4 * (i - 4)][j] = S;
            float p = (gr.x * __shfl(S, 4 * q + 0, 16) + gr.y * __shfl(S, 4 * q + 1, 16))
                    + (gr.z * __shfl(S, 4 * q + 2, 16) + gr.w * __shfl(S, 4 * q + 3, 16));
            p += __shfl_xor(p, 16);
            p += __shfl_xor(p, 32);
            S = p + sF[4 * w + i][j];
        }
    }
    // ---- reconstruct S at c%4 != 0: S_c = G1.S_{c-1} + d_{c-1} ----
    #pragma unroll
    for (int r = 1; r <= 3; ++r) {
        __syncthreads();
        const int g = tid >> 4;          // 0..15
        float ssp[16];
        #pragma unroll
        for (int m = 0; m < 4; ++m)
            *(float4*)&ssp[4 * m] = *(const float4*)&sS[4 * g + r - 1][4 * m];
        float acc = sdrev[QT + 4 * g + r - 1][15 - jj];
        #pragma unroll
        for (int i = 0; i < 16; ++i) acc += g1r[i] * ssp[i];
        sS[4 * g + r][jj] = acc;
    }
    __syncthreads();

    // ---- correction + store: out[c*64+k] = y_loc + V_k.S_c ----
    // V_k[j] = v_k[j]; thread owns k = 4*k4..4*k4+3 -> rows 4k4..4k4+3 of sVt
    {
        const int k4 = tid & 15;
        float rv0[16], rv1[16], rv2[16], rv3[16];
        #pragma unroll
        for (int m = 0; m < 4; ++m) {
            *(float4*)&rv0[4 * m] = *(const float4*)&sVt[4 * k4 + 0][4 * m];
            *(float4*)&rv1[4 * m] = *(const float4*)&sVt[4 * k4 + 1][4 * m];
            *(float4*)&rv2[4 * m] = *(const float4*)&sVt[4 * k4 + 2][4 * m];
            *(float4*)&rv3[4 * m] = *(const float4*)&sVt[4 * k4 + 3][4 * m];
        }
        float4* out4 = (float4*)(out + (long)cb * LCH);
        #pragma unroll
        for (int it = 0; it < 4; ++it) {
            const int f = it * 256 + tid;
            const int row = f >> 4;
            float ss[16];
            #pragma unroll
            for (int m = 0; m < 4; ++m)
                *(float4*)&ss[4 * m] = *(const float4*)&sS[row][4 * m];
            float4 y = *(const float4*)&y_s[row][4 * k4];
            #pragma unroll
            for (int j2 = 0; j2 < 16; ++j2) {
                y.x += rv0[j2] * ss[j2];
                y.y += rv1[j2] * ss[j2];
                y.z += rv2[j2] * ss[j2];
                y.w += rv3[j2] * ss[j2];
            }
            out4[f] = y;
        }
    }
}

extern "C" void kernel_launch(void* const* d_in, const int* in_sizes, int n_in,
                              void* d_out, int out_size, void* d_ws, size_t ws_size,
                              hipStream_t stream) {
    const float* u = (const float*)d_in[0];
    const float* A = (const float*)d_in[1];
    const float* B = (const float*)d_in[2];
    float* out = (float*)d_out;
    k_arx<<<NB, 256, 0, stream>>>(u, A, B, out);
}